// Round 20
// baseline (33.864 us; speedup 1.0000x reference)
//
#include <hip/hip_runtime.h>
#include <hip/hip_bf16.h>
#include <hip/hip_fp16.h>
#include <math.h>

#define NB   32
#define CIN  4
#define COUT 64
#define TT   6
#define VV   512
#define P_OFF (NB*COUT*TT*VV)   // out then p in d_out
#define SPLITS 8
#define CH   (VV/SPLITS)        // 64 softmax rows per block
#define NROW 24                 // c*6+t rows of x per batch
#define PKW  516                // pk row stride (u32)

typedef __attribute__((ext_vector_type(8))) short bf16x8;
typedef __attribute__((ext_vector_type(4))) float f32x4;

__device__ inline unsigned int pack2(float a, float b) {
    __hip_bfloat162 h = __float22bfloat162_rn(make_float2(a, b));
    return *reinterpret_cast<unsigned int*>(&h);
}

// ---------------------------------------------------------------------------
// Kernel 1 (fused, MFMA, inline-e): per block (s,n):
//  - compute e_j[0..512) (+l1_b) and e_i inline
//  - 64 softmax rows -> p (f32 global)
//  - y_part[r][w] = sum_i x[n,r,i]*p[n,i,w] via mfma_f32_16x16x32_bf16
// R12 body; ypart stored as f16 (pure intermediate, values O(1)) to halve
// its HBM write+read traffic.
// ---------------------------------------------------------------------------
__global__ __launch_bounds__(512, 4) void fused_kernel(
    const float* __restrict__ x,
    const int*   __restrict__ A,
    const float* __restrict__ conv_w,
    const float* __restrict__ conv_b,
    const float* __restrict__ l2_w,
    const float* __restrict__ l2_b,
    const float* __restrict__ l1_w,
    const float* __restrict__ l1_b,
    float*       __restrict__ p,
    __half*      __restrict__ ypart)
{
    __shared__ float xst[CH][33];            // [i][r], r24 = ones, 25..32 = 0
    __shared__ unsigned int pk[16][PKW];     // bf16-pair stage for one K-group
    __shared__ float W1s[CIN], W2s[CIN], cst[2], l2s[TT];
    __shared__ float ejl[VV];                // e_j + cst1 + l1b
    __shared__ float eil[CH];                // e_i for the block's 64 rows

    int s = blockIdx.x;                  // 8 chunks of 64 rows
    int n = blockIdx.y;
    int tid = threadIdx.x;
    int lane = tid & 63;
    int q = tid >> 6;                    // wave 0..7

    const int* mbase = A + (size_t)(n*8 + 7)*VV*VV;

    // issue sub-0 mask loads immediately (latency covered by e-compute)
    int4 mA0, mA1, mB0, mB1;
    {
        int i0 = s*CH + q*2;
        const int* mr = mbase + (size_t)i0*VV + lane*8;
        mA0 = *(const int4*)mr;       mA1 = *(const int4*)(mr + 4);
        mB0 = *(const int4*)(mr+VV);  mB1 = *(const int4*)(mr + VV + 4);
    }

    // ---- stage tiny weights ----
    if (tid < CIN) {
        float w1 = 0.f, w2 = 0.f;
        for (int o = 0; o < COUT; ++o) {
            w1 += l1_w[o]        * conv_w[o*CIN + tid];
            w2 += l1_w[COUT + o] * conv_w[o*CIN + tid];
        }
        W1s[tid] = w1; W2s[tid] = w2;
    }
    if (tid < TT) l2s[tid] = l2_w[tid];
    if (tid == CIN) {
        float B1 = 0.f, B2 = 0.f, S1 = 0.f, S2 = 0.f;
        for (int o = 0; o < COUT; ++o) {
            B1 += l1_w[o]        * conv_b[o];
            B2 += l1_w[COUT + o] * conv_b[o];
            S1 += l1_w[o];
            S2 += l1_w[COUT + o];
        }
        float Ls = 0.f;
        for (int t = 0; t < TT; ++t) Ls += l2_w[t];
        cst[0] = Ls*B1 + l2_b[0]*S1;
        cst[1] = Ls*B2 + l2_b[0]*S2 + l1_b[0];   // l1_b folded into e_j
    }
    __syncthreads();

    // ---- inline e: thread j computes e_j[j] and e_i[j] (keep if in chunk) --
    {
        int j = tid;
        float ei = cst[0], ej = cst[1];
        #pragma unroll
        for (int c = 0; c < CIN; ++c) {
            float w1 = W1s[c], w2 = W2s[c];
            #pragma unroll
            for (int t = 0; t < TT; ++t) {
                float lw = l2s[t];
                float xv = x[((size_t)(n*CIN + c)*TT + t)*VV + j];
                ei = fmaf(lw*w1, xv, ei);
                ej = fmaf(lw*w2, xv, ej);
            }
        }
        ejl[j] = ej;
        if ((j >> 6) == s) eil[j & 63] = ei;
    }

    // ---- stage xst[i][r] ----
    for (int idx = tid; idx < CH*33; idx += 512) {
        int r = idx >> 6;                // 0..32
        int i = idx & 63;
        float v = 0.f;
        if (r < NROW)       v = x[((size_t)n*NROW + r)*VV + s*CH + i];
        else if (r == NROW) v = 1.f;     // ones-row -> colsum
        xst[i][r] = v;
    }
    __syncthreads();                     // ejl/eil/xst ready

    float ejv[8];
    #pragma unroll
    for (int m = 0; m < 8; ++m) ejv[m] = ejl[lane*8 + m];

    f32x4 acc[2][4];
    #pragma unroll
    for (int mt = 0; mt < 2; ++mt)
        #pragma unroll
        for (int t = 0; t < 4; ++t) acc[mt][t] = (f32x4){0.f, 0.f, 0.f, 0.f};

    bf16x8 afr[2][2];                    // [Kgroup][mtile]

    for (int sub = 0; sub < 4; ++sub) {
        int ilA  = sub*16 + q*2;
        int i_gA = s*CH + ilA;

        int4 cA0 = mA0, cA1 = mA1, cB0 = mB0, cB1 = mB1;
        float biasA = eil[ilA], biasB = eil[ilA + 1];

        if (sub < 3) {                   // prefetch next sub's masks
            const int* mr = mbase + (size_t)(i_gA + 16)*VV + lane*8;
            mA0 = *(const int4*)mr;       mA1 = *(const int4*)(mr + 4);
            mB0 = *(const int4*)(mr+VV);  mB1 = *(const int4*)(mr + VV + 4);
        }

        // ---- softmax rows A & B (j = lane*8 + m) ----
        float svA[8], svB[8];
        int mkA[8] = {cA0.x,cA0.y,cA0.z,cA0.w, cA1.x,cA1.y,cA1.z,cA1.w};
        int mkB[8] = {cB0.x,cB0.y,cB0.z,cB0.w, cB1.x,cB1.y,cB1.z,cB1.w};
        #pragma unroll
        for (int m2 = 0; m2 < 8; ++m2) {
            float tA = biasA + ejv[m2]; tA = (tA >= 0.f) ? tA : 0.2f*tA;
            svA[m2] = (mkA[m2] == 0) ? -INFINITY : tA;
            float tB = biasB + ejv[m2]; tB = (tB >= 0.f) ? tB : 0.2f*tB;
            svB[m2] = (mkB[m2] == 0) ? -INFINITY : tB;
        }
        float mA = svA[0], mB = svB[0];
        #pragma unroll
        for (int m2 = 1; m2 < 8; ++m2) {
            mA = fmaxf(mA, svA[m2]); mB = fmaxf(mB, svB[m2]);
        }
        #pragma unroll
        for (int off = 32; off; off >>= 1) {
            mA = fmaxf(mA, __shfl_xor(mA, off));
            mB = fmaxf(mB, __shfl_xor(mB, off));
        }
        float sumA = 0.f, sumB = 0.f;
        if (mA > -INFINITY) {
            #pragma unroll
            for (int m2 = 0; m2 < 8; ++m2) { svA[m2] = __expf(svA[m2]-mA); sumA += svA[m2]; }
        } else {
            #pragma unroll
            for (int m2 = 0; m2 < 8; ++m2) svA[m2] = 0.f;
        }
        if (mB > -INFINITY) {
            #pragma unroll
            for (int m2 = 0; m2 < 8; ++m2) { svB[m2] = __expf(svB[m2]-mB); sumB += svB[m2]; }
        } else {
            #pragma unroll
            for (int m2 = 0; m2 < 8; ++m2) svB[m2] = 0.f;
        }
        #pragma unroll
        for (int off = 32; off; off >>= 1) {
            sumA += __shfl_xor(sumA, off);
            sumB += __shfl_xor(sumB, off);
        }
        float invA = (sumA > 0.f) ? 1.f/sumA : 0.f;
        float invB = (sumB > 0.f) ? 1.f/sumB : 0.f;
        #pragma unroll
        for (int m2 = 0; m2 < 8; ++m2) { svA[m2] *= invA; svB[m2] *= invB; }

        // global p stores (f32 exact, 16B/lane coalesced)
        float* prA = p + ((size_t)(n*VV + i_gA))*VV + lane*8;
        float4 pA03 = {svA[0],svA[1],svA[2],svA[3]}, pA47 = {svA[4],svA[5],svA[6],svA[7]};
        float4 pB03 = {svB[0],svB[1],svB[2],svB[3]}, pB47 = {svB[4],svB[5],svB[6],svB[7]};
        *(float4*)prA            = pA03;
        *(float4*)(prA + 4)      = pA47;
        *(float4*)(prA + VV)     = pB03;
        *(float4*)(prA + VV + 4) = pB47;

        // pk store: pair-row = (sub&1)*8 + q
        {
            int pr = (sub & 1)*8 + q;
            uint4 u0 = {pack2(svA[0],svB[0]), pack2(svA[1],svB[1]),
                        pack2(svA[2],svB[2]), pack2(svA[3],svB[3])};
            uint4 u1 = {pack2(svA[4],svB[4]), pack2(svA[5],svB[5]),
                        pack2(svA[6],svB[6]), pack2(svA[7],svB[7])};
            *(uint4*)&pk[pr][lane*8]     = u0;
            *(uint4*)&pk[pr][lane*8 + 4] = u1;
        }

        if (sub & 1) {
            __syncthreads();             // K-group pk complete

            if (sub == 1) {
                // build A-frags: k = g*32 + (lane>>4)*8 + j, m = mt*16+(lane&15)
                #pragma unroll
                for (int g = 0; g < 2; ++g)
                    #pragma unroll
                    for (int mt = 0; mt < 2; ++mt) {
                        int r  = mt*16 + (lane & 15);
                        int kb = g*32 + (lane >> 4)*8;
                        union { unsigned int u[4]; bf16x8 v; } ua;
                        #pragma unroll
                        for (int t = 0; t < 4; ++t)
                            ua.u[t] = pack2(xst[kb + 2*t][r], xst[kb + 2*t + 1][r]);
                        afr[g][mt] = ua.v;
                    }
            }

            int g = sub >> 1;            // K-group 0 or 1
            #pragma unroll
            for (int t = 0; t < 4; ++t) {
                int ncol = (q*4 + t)*16 + (lane & 15);
                union { unsigned int u[4]; bf16x8 v; } ub;
                #pragma unroll
                for (int jj = 0; jj < 4; ++jj)
                    ub.u[jj] = pk[(lane >> 4)*4 + jj][ncol];
                acc[0][t] = __builtin_amdgcn_mfma_f32_16x16x32_bf16(afr[g][0], ub.v, acc[0][t], 0, 0, 0);
                acc[1][t] = __builtin_amdgcn_mfma_f32_16x16x32_bf16(afr[g][1], ub.v, acc[1][t], 0, 0, 0);
            }
            if (sub == 1) __syncthreads();   // MFMA g0 done before sub2 overwrites pk
        }
    }

    // ---- write ypart (f16): D row = mt*16 + (lane>>4)*4 + reg, col = ncol --
    __half* yo = ypart + (size_t)(s*NB + n)*25*VV;
    #pragma unroll
    for (int mt = 0; mt < 2; ++mt)
        #pragma unroll
        for (int t = 0; t < 4; ++t) {
            int ncol = (q*4 + t)*16 + (lane & 15);
            #pragma unroll
            for (int reg = 0; reg < 4; ++reg) {
                int row = mt*16 + (lane >> 4)*4 + reg;
                if (row < 25)
                    yo[(size_t)row*VV + ncol] = __float2half(acc[mt][t][reg]);
            }
        }
}

// ---------------------------------------------------------------------------
// Kernel 2: out[n,o,t,w] = sum_c conv_w[o,c]*y[c*6+t,w] + conv_b[o]*y[24,w]
// 32-w chunks, grid (16,NB) = 512 blocks (2/CU). ypart (f16) read once.
// ---------------------------------------------------------------------------
__global__ __launch_bounds__(256) void expand_kernel(
    const __half* __restrict__ ypart,
    const float* __restrict__ conv_w,
    const float* __restrict__ conv_b,
    float*       __restrict__ out)
{
    __shared__ float ysm[25][32];
    __shared__ float wsm[COUT*CIN];
    __shared__ float bsm[COUT];

    int wc = blockIdx.x;                 // 16 w-chunks of 32
    int n  = blockIdx.y;
    int tid = threadIdx.x;

    if (tid < COUT*CIN) wsm[tid] = conv_w[tid];
    if (tid < COUT)     bsm[tid] = conv_b[tid];

    // stage + reduce splits: 25*32 halves as 4-wide groups
    for (int l4 = tid; l4 < 200; l4 += 256) {
        int r = l4 >> 3, w8 = l4 & 7;
        float4 a = {0.f, 0.f, 0.f, 0.f};
        #pragma unroll
        for (int s = 0; s < SPLITS; ++s) {
            const __half2* h2 = (const __half2*)(ypart +
                ((size_t)(s*NB + n)*25 + r)*VV + wc*32 + w8*4);
            float2 lo = __half22float2(h2[0]);
            float2 hi = __half22float2(h2[1]);
            a.x += lo.x; a.y += lo.y; a.z += hi.x; a.w += hi.y;
        }
        *(float4*)&ysm[r][w8*4] = a;
    }
    __syncthreads();

    int w  = tid & 31;
    int og = tid >> 5;                   // 8 groups x 8 o

    float y[25];
    #pragma unroll
    for (int r = 0; r < 25; ++r) y[r] = ysm[r][w];

    #pragma unroll
    for (int oo = 0; oo < 8; ++oo) {
        int o = og*8 + oo;
        float wb[CIN];
        #pragma unroll
        for (int c = 0; c < CIN; ++c) wb[c] = wsm[o*CIN + c];
        float bo = bsm[o];
        #pragma unroll
        for (int t = 0; t < TT; ++t) {
            float val = bo * y[24];
            #pragma unroll
            for (int c = 0; c < CIN; ++c) val = fmaf(wb[c], y[c*TT + t], val);
            out[((size_t)(n*COUT + o)*TT + t)*VV + wc*32 + w] = val;
        }
    }
}

// ---------------------------------------------------------------------------
extern "C" void kernel_launch(void* const* d_in, const int* in_sizes, int n_in,
                              void* d_out, int out_size, void* d_ws, size_t ws_size,
                              hipStream_t stream)
{
    const float* x      = (const float*)d_in[0];
    const int*   A      = (const int*)  d_in[1];
    const float* conv_w = (const float*)d_in[2];
    const float* conv_b = (const float*)d_in[3];
    const float* l2_w   = (const float*)d_in[4];
    const float* l2_b   = (const float*)d_in[5];
    const float* l1_w   = (const float*)d_in[6];
    const float* l1_b   = (const float*)d_in[7];

    float* out = (float*)d_out;
    float* pP  = out + P_OFF;              // p region of d_out
    __half* yp = (__half*)d_ws;            // SPLITS*NB*25*VV f16 = 6.55 MB

    dim3 gf(SPLITS, NB);                   // 256 blocks x 512 thr
    fused_kernel<<<gf, 512, 0, stream>>>(x, A, conv_w, conv_b, l2_w, l2_b,
                                         l1_w, l1_b, pP, yp);

    dim3 ge(16, NB);                       // 512 blocks
    expand_kernel<<<ge, 256, 0, stream>>>(yp, conv_w, conv_b, out);
}

// Round 21
// 33.489 us; speedup vs baseline: 1.0112x; 1.0112x over previous
//
#include <hip/hip_runtime.h>
#include <hip/hip_bf16.h>
#include <math.h>

#define NB   32
#define CIN  4
#define COUT 64
#define TT   6
#define VV   512
#define P_OFF (NB*COUT*TT*VV)   // out then p in d_out
#define SPLITS 8
#define CH   (VV/SPLITS)        // 64 softmax rows per block
#define NROW 24                 // c*6+t rows of x per batch
#define PKW  516                // pk row stride (u32)

typedef __attribute__((ext_vector_type(8))) short bf16x8;
typedef __attribute__((ext_vector_type(4))) float f32x4;

__device__ inline unsigned int pack2(float a, float b) {
    __hip_bfloat162 h = __float22bfloat162_rn(make_float2(a, b));
    return *reinterpret_cast<unsigned int*>(&h);
}

// ---------------------------------------------------------------------------
// Kernel 1 (fused, MFMA, inline-e): per block (s,n):
//  - compute e_j[0..512) (+l1_b) and e_i inline
//  - 64 softmax rows -> p (f32 global)
//  - y_part[r][w] = sum_i x[n,r,i]*p[n,i,w] via mfma_f32_16x16x32_bf16
// R12 body. Launch bounds relaxed to (512,2): grid = 1 block/CU always, so
// the old (512,4) 128-VGPR cap bought nothing and starved the scheduler.
// ---------------------------------------------------------------------------
__global__ __launch_bounds__(512, 2) void fused_kernel(
    const float* __restrict__ x,
    const int*   __restrict__ A,
    const float* __restrict__ conv_w,
    const float* __restrict__ conv_b,
    const float* __restrict__ l2_w,
    const float* __restrict__ l2_b,
    const float* __restrict__ l1_w,
    const float* __restrict__ l1_b,
    float*       __restrict__ p,
    float*       __restrict__ ypart)
{
    __shared__ float xst[CH][33];            // [i][r], r24 = ones, 25..32 = 0
    __shared__ unsigned int pk[16][PKW];     // bf16-pair stage for one K-group
    __shared__ float W1s[CIN], W2s[CIN], cst[2], l2s[TT];
    __shared__ float ejl[VV];                // e_j + cst1 + l1b
    __shared__ float eil[CH];                // e_i for the block's 64 rows

    int s = blockIdx.x;                  // 8 chunks of 64 rows
    int n = blockIdx.y;
    int tid = threadIdx.x;
    int lane = tid & 63;
    int q = tid >> 6;                    // wave 0..7

    const int* mbase = A + (size_t)(n*8 + 7)*VV*VV;

    // issue sub-0 mask loads immediately (latency covered by e-compute)
    int4 mA0, mA1, mB0, mB1;
    {
        int i0 = s*CH + q*2;
        const int* mr = mbase + (size_t)i0*VV + lane*8;
        mA0 = *(const int4*)mr;       mA1 = *(const int4*)(mr + 4);
        mB0 = *(const int4*)(mr+VV);  mB1 = *(const int4*)(mr + VV + 4);
    }

    // ---- stage tiny weights ----
    if (tid < CIN) {
        float w1 = 0.f, w2 = 0.f;
        for (int o = 0; o < COUT; ++o) {
            w1 += l1_w[o]        * conv_w[o*CIN + tid];
            w2 += l1_w[COUT + o] * conv_w[o*CIN + tid];
        }
        W1s[tid] = w1; W2s[tid] = w2;
    }
    if (tid < TT) l2s[tid] = l2_w[tid];
    if (tid == CIN) {
        float B1 = 0.f, B2 = 0.f, S1 = 0.f, S2 = 0.f;
        for (int o = 0; o < COUT; ++o) {
            B1 += l1_w[o]        * conv_b[o];
            B2 += l1_w[COUT + o] * conv_b[o];
            S1 += l1_w[o];
            S2 += l1_w[COUT + o];
        }
        float Ls = 0.f;
        for (int t = 0; t < TT; ++t) Ls += l2_w[t];
        cst[0] = Ls*B1 + l2_b[0]*S1;
        cst[1] = Ls*B2 + l2_b[0]*S2 + l1_b[0];   // l1_b folded into e_j
    }
    __syncthreads();

    // ---- inline e: thread j computes e_j[j] and e_i[j] (keep if in chunk) --
    {
        int j = tid;
        float ei = cst[0], ej = cst[1];
        #pragma unroll
        for (int c = 0; c < CIN; ++c) {
            float w1 = W1s[c], w2 = W2s[c];
            #pragma unroll
            for (int t = 0; t < TT; ++t) {
                float lw = l2s[t];
                float xv = x[((size_t)(n*CIN + c)*TT + t)*VV + j];
                ei = fmaf(lw*w1, xv, ei);
                ej = fmaf(lw*w2, xv, ej);
            }
        }
        ejl[j] = ej;
        if ((j >> 6) == s) eil[j & 63] = ei;
    }

    // ---- stage xst[i][r] ----
    for (int idx = tid; idx < CH*33; idx += 512) {
        int r = idx >> 6;                // 0..32
        int i = idx & 63;
        float v = 0.f;
        if (r < NROW)       v = x[((size_t)n*NROW + r)*VV + s*CH + i];
        else if (r == NROW) v = 1.f;     // ones-row -> colsum
        xst[i][r] = v;
    }
    __syncthreads();                     // ejl/eil/xst ready

    float ejv[8];
    #pragma unroll
    for (int m = 0; m < 8; ++m) ejv[m] = ejl[lane*8 + m];

    f32x4 acc[2][4];
    #pragma unroll
    for (int mt = 0; mt < 2; ++mt)
        #pragma unroll
        for (int t = 0; t < 4; ++t) acc[mt][t] = (f32x4){0.f, 0.f, 0.f, 0.f};

    bf16x8 afr[2][2];                    // [Kgroup][mtile]

    for (int sub = 0; sub < 4; ++sub) {
        int ilA  = sub*16 + q*2;
        int i_gA = s*CH + ilA;

        int4 cA0 = mA0, cA1 = mA1, cB0 = mB0, cB1 = mB1;
        float biasA = eil[ilA], biasB = eil[ilA + 1];

        if (sub < 3) {                   // prefetch next sub's masks
            const int* mr = mbase + (size_t)(i_gA + 16)*VV + lane*8;
            mA0 = *(const int4*)mr;       mA1 = *(const int4*)(mr + 4);
            mB0 = *(const int4*)(mr+VV);  mB1 = *(const int4*)(mr + VV + 4);
        }

        // ---- softmax rows A & B (j = lane*8 + m) ----
        float svA[8], svB[8];
        int mkA[8] = {cA0.x,cA0.y,cA0.z,cA0.w, cA1.x,cA1.y,cA1.z,cA1.w};
        int mkB[8] = {cB0.x,cB0.y,cB0.z,cB0.w, cB1.x,cB1.y,cB1.z,cB1.w};
        #pragma unroll
        for (int m2 = 0; m2 < 8; ++m2) {
            float tA = biasA + ejv[m2]; tA = (tA >= 0.f) ? tA : 0.2f*tA;
            svA[m2] = (mkA[m2] == 0) ? -INFINITY : tA;
            float tB = biasB + ejv[m2]; tB = (tB >= 0.f) ? tB : 0.2f*tB;
            svB[m2] = (mkB[m2] == 0) ? -INFINITY : tB;
        }
        float mA = svA[0], mB = svB[0];
        #pragma unroll
        for (int m2 = 1; m2 < 8; ++m2) {
            mA = fmaxf(mA, svA[m2]); mB = fmaxf(mB, svB[m2]);
        }
        #pragma unroll
        for (int off = 32; off; off >>= 1) {
            mA = fmaxf(mA, __shfl_xor(mA, off));
            mB = fmaxf(mB, __shfl_xor(mB, off));
        }
        float sumA = 0.f, sumB = 0.f;
        if (mA > -INFINITY) {
            #pragma unroll
            for (int m2 = 0; m2 < 8; ++m2) { svA[m2] = __expf(svA[m2]-mA); sumA += svA[m2]; }
        } else {
            #pragma unroll
            for (int m2 = 0; m2 < 8; ++m2) svA[m2] = 0.f;
        }
        if (mB > -INFINITY) {
            #pragma unroll
            for (int m2 = 0; m2 < 8; ++m2) { svB[m2] = __expf(svB[m2]-mB); sumB += svB[m2]; }
        } else {
            #pragma unroll
            for (int m2 = 0; m2 < 8; ++m2) svB[m2] = 0.f;
        }
        #pragma unroll
        for (int off = 32; off; off >>= 1) {
            sumA += __shfl_xor(sumA, off);
            sumB += __shfl_xor(sumB, off);
        }
        float invA = (sumA > 0.f) ? 1.f/sumA : 0.f;
        float invB = (sumB > 0.f) ? 1.f/sumB : 0.f;
        #pragma unroll
        for (int m2 = 0; m2 < 8; ++m2) { svA[m2] *= invA; svB[m2] *= invB; }

        // global p stores (f32 exact, 16B/lane coalesced)
        float* prA = p + ((size_t)(n*VV + i_gA))*VV + lane*8;
        float4 pA03 = {svA[0],svA[1],svA[2],svA[3]}, pA47 = {svA[4],svA[5],svA[6],svA[7]};
        float4 pB03 = {svB[0],svB[1],svB[2],svB[3]}, pB47 = {svB[4],svB[5],svB[6],svB[7]};
        *(float4*)prA            = pA03;
        *(float4*)(prA + 4)      = pA47;
        *(float4*)(prA + VV)     = pB03;
        *(float4*)(prA + VV + 4) = pB47;

        // pk store: pair-row = (sub&1)*8 + q
        {
            int pr = (sub & 1)*8 + q;
            uint4 u0 = {pack2(svA[0],svB[0]), pack2(svA[1],svB[1]),
                        pack2(svA[2],svB[2]), pack2(svA[3],svB[3])};
            uint4 u1 = {pack2(svA[4],svB[4]), pack2(svA[5],svB[5]),
                        pack2(svA[6],svB[6]), pack2(svA[7],svB[7])};
            *(uint4*)&pk[pr][lane*8]     = u0;
            *(uint4*)&pk[pr][lane*8 + 4] = u1;
        }

        if (sub & 1) {
            __syncthreads();             // K-group pk complete

            if (sub == 1) {
                // build A-frags: k = g*32 + (lane>>4)*8 + j, m = mt*16+(lane&15)
                #pragma unroll
                for (int g = 0; g < 2; ++g)
                    #pragma unroll
                    for (int mt = 0; mt < 2; ++mt) {
                        int r  = mt*16 + (lane & 15);
                        int kb = g*32 + (lane >> 4)*8;
                        union { unsigned int u[4]; bf16x8 v; } ua;
                        #pragma unroll
                        for (int t = 0; t < 4; ++t)
                            ua.u[t] = pack2(xst[kb + 2*t][r], xst[kb + 2*t + 1][r]);
                        afr[g][mt] = ua.v;
                    }
            }

            int g = sub >> 1;            // K-group 0 or 1
            #pragma unroll
            for (int t = 0; t < 4; ++t) {
                int ncol = (q*4 + t)*16 + (lane & 15);
                union { unsigned int u[4]; bf16x8 v; } ub;
                #pragma unroll
                for (int jj = 0; jj < 4; ++jj)
                    ub.u[jj] = pk[(lane >> 4)*4 + jj][ncol];
                acc[0][t] = __builtin_amdgcn_mfma_f32_16x16x32_bf16(afr[g][0], ub.v, acc[0][t], 0, 0, 0);
                acc[1][t] = __builtin_amdgcn_mfma_f32_16x16x32_bf16(afr[g][1], ub.v, acc[1][t], 0, 0, 0);
            }
            if (sub == 1) __syncthreads();   // MFMA g0 done before sub2 overwrites pk
        }
    }

    // ---- write ypart: D row = mt*16 + (lane>>4)*4 + reg, col = ncol ----
    float* yo = ypart + (size_t)(s*NB + n)*25*VV;
    #pragma unroll
    for (int mt = 0; mt < 2; ++mt)
        #pragma unroll
        for (int t = 0; t < 4; ++t) {
            int ncol = (q*4 + t)*16 + (lane & 15);
            #pragma unroll
            for (int reg = 0; reg < 4; ++reg) {
                int row = mt*16 + (lane >> 4)*4 + reg;
                if (row < 25)
                    yo[(size_t)row*VV + ncol] = acc[mt][t][reg];
            }
        }
}

// ---------------------------------------------------------------------------
// Kernel 2: out[n,o,t,w] = sum_c conv_w[o,c]*y[c*6+t,w] + conv_b[o]*y[24,w]
// 32-w chunks, grid (16,NB) = 512 blocks (2/CU). ypart read exactly once.
// ---------------------------------------------------------------------------
__global__ __launch_bounds__(256) void expand_kernel(
    const float* __restrict__ ypart,
    const float* __restrict__ conv_w,
    const float* __restrict__ conv_b,
    float*       __restrict__ out)
{
    __shared__ float ysm[25][32];
    __shared__ float wsm[COUT*CIN];
    __shared__ float bsm[COUT];

    int wc = blockIdx.x;                 // 16 w-chunks of 32
    int n  = blockIdx.y;
    int tid = threadIdx.x;

    if (tid < COUT*CIN) wsm[tid] = conv_w[tid];
    if (tid < COUT)     bsm[tid] = conv_b[tid];

    // stage + reduce splits: 25*32 = 800 floats as 200 float4
    for (int l4 = tid; l4 < 200; l4 += 256) {
        int r = l4 >> 3, w8 = l4 & 7;
        float4 a = {0.f, 0.f, 0.f, 0.f};
        #pragma unroll
        for (int s = 0; s < SPLITS; ++s) {
            float4 v = *(const float4*)(ypart +
                ((size_t)(s*NB + n)*25 + r)*VV + wc*32 + w8*4);
            a.x += v.x; a.y += v.y; a.z += v.z; a.w += v.w;
        }
        *(float4*)&ysm[r][w8*4] = a;
    }
    __syncthreads();

    int w  = tid & 31;
    int og = tid >> 5;                   // 8 groups x 8 o

    float y[25];
    #pragma unroll
    for (int r = 0; r < 25; ++r) y[r] = ysm[r][w];

    #pragma unroll
    for (int oo = 0; oo < 8; ++oo) {
        int o = og*8 + oo;
        float wb[CIN];
        #pragma unroll
        for (int c = 0; c < CIN; ++c) wb[c] = wsm[o*CIN + c];
        float bo = bsm[o];
        #pragma unroll
        for (int t = 0; t < TT; ++t) {
            float val = bo * y[24];
            #pragma unroll
            for (int c = 0; c < CIN; ++c) val = fmaf(wb[c], y[c*TT + t], val);
            out[((size_t)(n*COUT + o)*TT + t)*VV + wc*32 + w] = val;
        }
    }
}

// ---------------------------------------------------------------------------
extern "C" void kernel_launch(void* const* d_in, const int* in_sizes, int n_in,
                              void* d_out, int out_size, void* d_ws, size_t ws_size,
                              hipStream_t stream)
{
    const float* x      = (const float*)d_in[0];
    const int*   A      = (const int*)  d_in[1];
    const float* conv_w = (const float*)d_in[2];
    const float* conv_b = (const float*)d_in[3];
    const float* l2_w   = (const float*)d_in[4];
    const float* l2_b   = (const float*)d_in[5];
    const float* l1_w   = (const float*)d_in[6];
    const float* l1_b   = (const float*)d_in[7];

    float* out = (float*)d_out;
    float* pP  = out + P_OFF;              // p region of d_out
    float* yp  = (float*)d_ws;             // SPLITS*NB*25*VV f32 = 13.1 MB

    dim3 gf(SPLITS, NB);                   // 256 blocks x 512 thr (1/CU)
    fused_kernel<<<gf, 512, 0, stream>>>(x, A, conv_w, conv_b, l2_w, l2_b,
                                         l1_w, l1_b, pP, yp);

    dim3 ge(16, NB);                       // 512 blocks
    expand_kernel<<<ge, 256, 0, stream>>>(yp, conv_w, conv_b, out);
}